// Round 1
// 123.312 us; speedup vs baseline: 1.0136x; 1.0136x over previous
//
#include <hip/hip_runtime.h>

#define BB    4
#define CINT  64
#define HH    128
#define WW    128
#define COUTN 64
#define DGN   8
#define CGN   8
#define KKN   9
#define HOWO  16384
#define HWSZ  (HH * WW)
#define HP    132
#define WP    132
#define HWP   (HP * WP)          // 17424 granules per (b,g) plane, 2-wide zero border
#define NXG   (BB * DGN * HWP)   // 557568 granules = 8,921,088 B
#define NCHUNK 18                // K = 576 = 18 * 32
#define NWBLK  18                // weight-prep blocks (18*256 = 4608 entries)

typedef __bf16 bf16x8 __attribute__((ext_vector_type(8)));
typedef float  f32x4  __attribute__((ext_vector_type(4)));

static __device__ __forceinline__ ushort f2bf(float f) {
    unsigned u = __builtin_bit_cast(unsigned, f);
    u += 0x7fffu + ((u >> 16) & 1u);      // round-to-nearest-even
    return (ushort)(u >> 16);
}

// ---- fused prep: blocks [0,18) pack weights into MFMA A-fragment order;
// blocks [18,..) build zero-padded bf16 image xh [B][DG][132][132][CG].
__global__ __launch_bounds__(256) void prep(
    const float* __restrict__ x, const float* __restrict__ wgt,
    uint4* __restrict__ xh, uint4* __restrict__ wq)
{
    const int bid = blockIdx.x;
    const int tid = threadIdx.x;
    if (bid < NWBLK) {
        int i = bid * 256 + tid;            // 0..4607
        int lane = i & 63;
        int mt   = (i >> 6) & 3;
        int kt   = i >> 8;
        int m = lane & 15, quad = lane >> 4;
        int o = mt * 16 + m;
        union { ushort u[8]; uint4 v; } pk;
#pragma unroll
        for (int j = 0; j < 8; ++j) {
            int k   = kt * 32 + quad * 8 + j;
            int gkk = k >> 3, c = k & 7;
            int g   = gkk / 9, kk = gkk - 9 * g;
            pk.u[j] = f2bf(wgt[(o * CINT + g * CGN + c) * KKN + kk]);
        }
        wq[i] = pk.v;
        return;
    }
    int j = (bid - NWBLK) * 256 + tid;      // granule id
    if (j >= NXG) return;
    int bg = j / HWP;
    int r  = j - bg * HWP;
    int yp = r / WP;
    int xp = r - yp * WP;
    union { ushort u[8]; uint4 v; } pk;
    pk.v.x = pk.v.y = pk.v.z = pk.v.w = 0u;
    if (yp >= 2 && yp <= 129 && xp >= 2 && xp <= 129) {
        const float* src = x + (size_t)bg * CGN * HWSZ + (yp - 2) * WW + (xp - 2);
#pragma unroll
        for (int c = 0; c < CGN; ++c) pk.u[c] = f2bf(src[c * HWSZ]);
    }
    xh[j] = pk.v;
}

// ---- main: each wave owns 16 pixels; lane (q=lane>>4, n=lane&15) samples
// (pixel n, gkk = ch*4+q) -> its 8-channel B-fragment directly. No LDS, no barriers.
__global__ __launch_bounds__(256, 4) void dcn_mfma(
    const uint4* __restrict__ xh, const float* __restrict__ off,
    const uint4* __restrict__ wq, const float* __restrict__ bias,
    float* __restrict__ out)
{
    const int tid  = threadIdx.x;
    const int wave = tid >> 6;
    const int lane = tid & 63;
    const int q    = lane >> 4;         // k-quarter within 32-K chunk
    const int n    = lane & 15;         // pixel within wave tile

    const int wid     = blockIdx.x * 4 + wave;     // 0..4095
    const int pixbase = wid * 16;
    const int b       = pixbase >> 14;
    const int rem     = (pixbase & 16383) + n;
    const int ho = rem >> 7, wo = rem & 127;
    const float fy0 = (float)(ho - 1);
    const float fx0 = (float)(wo - 1);

    // offset float index: (b*72 + gkk)*2*HOWO + rem (dy), +HOWO (dx); gkk = ch*4+q
    const float* offp = off + (size_t)(b * 72 + q) * 2 * HOWO + rem;

    float lofy[4], lofx[4];             // rotating 4-deep offset prefetch
#pragma unroll
    for (int c0 = 0; c0 < 4; ++c0) {
        lofy[c0] = offp[(size_t)c0 * 8 * HOWO];
        lofx[c0] = offp[(size_t)c0 * 8 * HOWO + HOWO];
    }

    f32x4 acc[4];
#pragma unroll
    for (int mt = 0; mt < 4; ++mt) acc[mt] = (f32x4){0.f, 0.f, 0.f, 0.f};

    const int xbase = b * DGN * HWP;    // granule base for batch b

    int g = 0, kk = q;                  // incremental gkk -> (g, kk)
    uint4 c00, c01, c10, c11, n00, n01, n10, n11;
    float w00, w01, w10, w11, v00, v01, v10, v11;

    auto issue = [&](int ch, uint4& r00, uint4& r01, uint4& r10, uint4& r11,
                     float& u00, float& u01, float& u10, float& u11) {
        int kh = (kk * 11) >> 5;        // kk/3 for kk in [0,9)
        int kw = kk - 3 * kh;
        float py  = fy0 + (float)kh + lofy[ch & 3];
        float pxx = fx0 + (float)kw + lofx[ch & 3];
        float y0f = floorf(py), x0f = floorf(pxx);
        float ly = py - y0f, lx = pxx - x0f;
        float hy = 1.f - ly, hx = 1.f - lx;
        u00 = hy * hx; u01 = hy * lx; u10 = ly * hx; u11 = ly * lx;
        int y0 = (int)y0f, x0 = (int)x0f;
        // clamp into [-2, 128]: with the 2-wide zero border every OOB corner reads 0
        y0 = min(max(y0, -2), HH);
        x0 = min(max(x0, -2), WW);
        const uint4* p = xh + (xbase + g * HWP + (y0 + 2) * WP + (x0 + 2));
        r00 = p[0]; r01 = p[1]; r10 = p[WP]; r11 = p[WP + 1];
        kk += 4; if (kk >= KKN) { kk -= KKN; ++g; }   // advance gkk by 4
    };

    issue(0, c00, c01, c10, c11, w00, w01, w10, w11);

#pragma unroll
    for (int ch = 0; ch < NCHUNK; ++ch) {
        if (ch + 4 < NCHUNK) {          // offset prefetch, 4 chunks ahead
            lofy[(ch + 4) & 3] = offp[(size_t)(ch + 4) * 8 * HOWO];
            lofx[(ch + 4) & 3] = offp[(size_t)(ch + 4) * 8 * HOWO + HOWO];
        }
        if (ch + 1 < NCHUNK)            // gather issue, 1 chunk ahead
            issue(ch + 1, n00, n01, n10, n11, v00, v01, v10, v11);

        const __bf16* a00 = (const __bf16*)&c00;
        const __bf16* a01 = (const __bf16*)&c01;
        const __bf16* a10 = (const __bf16*)&c10;
        const __bf16* a11 = (const __bf16*)&c11;
        bf16x8 bfrag;
#pragma unroll
        for (int cc = 0; cc < 8; ++cc) {
            float v = w00 * (float)a00[cc] + w01 * (float)a01[cc]
                    + w10 * (float)a10[cc] + w11 * (float)a11[cc];
            bfrag[cc] = (__bf16)v;      // compiler emits v_cvt_pk_bf16_f32 (RNE)
        }
#pragma unroll
        for (int mt = 0; mt < 4; ++mt) {
            bf16x8 afrag = __builtin_bit_cast(bf16x8, wq[(ch * 4 + mt) * 64 + lane]);
            acc[mt] = __builtin_amdgcn_mfma_f32_16x16x32_bf16(afrag, bfrag, acc[mt], 0, 0, 0);
        }
        if (ch + 1 < NCHUNK) {
            c00 = n00; c01 = n01; c10 = n10; c11 = n11;
            w00 = v00; w01 = v01; w10 = v10; w11 = v11;
        }
    }

    // C/D layout: col = lane&15 (pixel), row = q*4 + r (out channel within 16-tile)
    const int rem_out = (pixbase & 16383) + n;
    float* outp = out + (size_t)b * COUTN * HOWO + rem_out;
#pragma unroll
    for (int mt = 0; mt < 4; ++mt) {
        f32x4 bv = *(const f32x4*)(bias + mt * 16 + q * 4);
#pragma unroll
        for (int r = 0; r < 4; ++r) {
            int o = mt * 16 + q * 4 + r;
            outp[(size_t)o * HOWO] = acc[mt][r] + bv[r];
        }
    }
}

extern "C" void kernel_launch(void* const* d_in, const int* in_sizes, int n_in,
                              void* d_out, int out_size, void* d_ws, size_t ws_size,
                              hipStream_t stream) {
    const float* x    = (const float*)d_in[0];
    const float* off  = (const float*)d_in[1];
    const float* wgt  = (const float*)d_in[2];
    const float* bias = (const float*)d_in[3];
    float* out = (float*)d_out;

    uint4* xh = (uint4*)d_ws;                                 // 8,921,088 B
    uint4* wq = (uint4*)((char*)d_ws + (size_t)NXG * 16);     // 73,728 B

    const int xblocks = (NXG + 255) / 256;                    // 2178
    prep<<<dim3(NWBLK + xblocks), dim3(256), 0, stream>>>(x, wgt, xh, wq);
    dcn_mfma<<<dim3(BB * HOWO / 64), dim3(256), 0, stream>>>(xh, off, wq, bias, out);
}

// Round 2
// 123.132 us; speedup vs baseline: 1.0151x; 1.0015x over previous
//
#include <hip/hip_runtime.h>

#define BB    4
#define CINT  64
#define HH    128
#define WW    128
#define COUTN 64
#define DGN   8
#define CGN   8
#define KKN   9
#define HOWO  16384
#define HWSZ  (HH * WW)
#define HP    132
#define WP    132
#define HWP   (HP * WP)          // 17424 granules per (b,g) plane, 2-wide zero border
#define NXG   (BB * DGN * HWP)   // 557568 granules = 8,921,088 B
#define NCHUNK 18                // K = 576 = 18 * 32
#define NCHALF 9                 // chunks per K-half wave
#define NWBLK  18                // weight-prep blocks (18*256 = 4608 entries)

typedef __bf16 bf16x8 __attribute__((ext_vector_type(8)));
typedef float  f32x4  __attribute__((ext_vector_type(4)));

static __device__ __forceinline__ ushort f2bf(float f) {
    unsigned u = __builtin_bit_cast(unsigned, f);
    u += 0x7fffu + ((u >> 16) & 1u);      // round-to-nearest-even
    return (ushort)(u >> 16);
}

// ---- fused prep: blocks [0,18) pack weights into MFMA A-fragment order;
// blocks [18,..) build zero-padded bf16 image xh [B][DG][132][132][CG].
__global__ __launch_bounds__(256) void prep(
    const float* __restrict__ x, const float* __restrict__ wgt,
    uint4* __restrict__ xh, uint4* __restrict__ wq)
{
    const int bid = blockIdx.x;
    const int tid = threadIdx.x;
    if (bid < NWBLK) {
        int i = bid * 256 + tid;            // 0..4607
        int lane = i & 63;
        int mt   = (i >> 6) & 3;
        int kt   = i >> 8;
        int m = lane & 15, quad = lane >> 4;
        int o = mt * 16 + m;
        union { ushort u[8]; uint4 v; } pk;
#pragma unroll
        for (int j = 0; j < 8; ++j) {
            int k   = kt * 32 + quad * 8 + j;
            int gkk = k >> 3, c = k & 7;
            int g   = gkk / 9, kk = gkk - 9 * g;
            pk.u[j] = f2bf(wgt[(o * CINT + g * CGN + c) * KKN + kk]);
        }
        wq[i] = pk.v;
        return;
    }
    int j = (bid - NWBLK) * 256 + tid;      // granule id
    if (j >= NXG) return;
    int bg = j / HWP;
    int r  = j - bg * HWP;
    int yp = r / WP;
    int xp = r - yp * WP;
    union { ushort u[8]; uint4 v; } pk;
    pk.v.x = pk.v.y = pk.v.z = pk.v.w = 0u;
    if (yp >= 2 && yp <= 129 && xp >= 2 && xp <= 129) {
        const float* src = x + (size_t)bg * CGN * HWSZ + (yp - 2) * WW + (xp - 2);
#pragma unroll
        for (int c = 0; c < CGN; ++c) pk.u[c] = f2bf(src[c * HWSZ]);
    }
    xh[j] = pk.v;
}

// ---- main: block = 4 waves = 2 pixel-tiles x 2 K-halves.
// Wave (tile, half): 16 pixels, chunks [half*9, half*9+9). Lane (q=lane>>4, n=lane&15)
// samples (pixel n, gkk = ch*4+q) -> its 8-channel B-fragment directly in-register.
// Partial sums combined through 8 KB LDS, one barrier.
__global__ __launch_bounds__(256, 8) void dcn_mfma(
    const uint4* __restrict__ xh, const float* __restrict__ off,
    const uint4* __restrict__ wq, const float* __restrict__ bias,
    float* __restrict__ out)
{
    __shared__ f32x4 lred[2][4][64];    // [tile][mt][lane]

    const int tid  = threadIdx.x;
    const int wave = tid >> 6;
    const int lane = tid & 63;
    const int tile = wave >> 1;
    const int half = wave & 1;
    const int ch0  = half * NCHALF;     // first chunk of this wave's K-half
    const int q    = lane >> 4;         // k-quarter within 32-K chunk
    const int n    = lane & 15;         // pixel within wave tile

    const int pixbase = blockIdx.x * 32 + tile * 16;
    const int b       = pixbase >> 14;
    const int rem     = (pixbase & 16383) + n;
    const int ho = rem >> 7, wo = rem & 127;
    const float fy0 = (float)(ho - 1);
    const float fx0 = (float)(wo - 1);

    // offset float index: (b*72 + gkk)*2*HOWO + rem (dy), +HOWO (dx); gkk = ch*4+q
    const float* offp = off + (size_t)(b * 72 + ch0 * 4 + q) * 2 * HOWO + rem;

    float lofy[4], lofx[4];             // rotating 4-deep offset prefetch
#pragma unroll
    for (int c0 = 0; c0 < 4; ++c0) {
        lofy[c0] = offp[(size_t)c0 * 8 * HOWO];
        lofx[c0] = offp[(size_t)c0 * 8 * HOWO + HOWO];
    }

    f32x4 acc[4];
#pragma unroll
    for (int mt = 0; mt < 4; ++mt) acc[mt] = (f32x4){0.f, 0.f, 0.f, 0.f};

    const int xbase = b * DGN * HWP;    // granule base for batch b

    const int gkk0 = ch0 * 4 + q;
    int g = gkk0 / KKN, kk = gkk0 - KKN * (gkk0 / KKN);
    uint4 c00, c01, c10, c11, n00, n01, n10, n11;
    float w00, w01, w10, w11, v00, v01, v10, v11;

    auto issue = [&](int cc, uint4& r00, uint4& r01, uint4& r10, uint4& r11,
                     float& u00, float& u01, float& u10, float& u11) {
        int kh = (kk * 11) >> 5;        // kk/3 for kk in [0,9)
        int kw = kk - 3 * kh;
        float py  = fy0 + (float)kh + lofy[cc & 3];
        float pxx = fx0 + (float)kw + lofx[cc & 3];
        float y0f = floorf(py), x0f = floorf(pxx);
        float ly = py - y0f, lx = pxx - x0f;
        float hy = 1.f - ly, hx = 1.f - lx;
        u00 = hy * hx; u01 = hy * lx; u10 = ly * hx; u11 = ly * lx;
        int y0 = (int)y0f, x0 = (int)x0f;
        // clamp into [-2, 128]: with the 2-wide zero border every OOB corner reads 0
        y0 = min(max(y0, -2), HH);
        x0 = min(max(x0, -2), WW);
        const uint4* p = xh + (xbase + g * HWP + (y0 + 2) * WP + (x0 + 2));
        r00 = p[0]; r01 = p[1]; r10 = p[WP]; r11 = p[WP + 1];
        kk += 4; if (kk >= KKN) { kk -= KKN; ++g; }   // advance gkk by 4
    };

    issue(0, c00, c01, c10, c11, w00, w01, w10, w11);

#pragma unroll
    for (int cc = 0; cc < NCHALF; ++cc) {
        if (cc + 4 < NCHALF) {          // offset prefetch, 4 chunks ahead
            lofy[(cc + 4) & 3] = offp[(size_t)(cc + 4) * 8 * HOWO];
            lofx[(cc + 4) & 3] = offp[(size_t)(cc + 4) * 8 * HOWO + HOWO];
        }
        if (cc + 1 < NCHALF)            // gather issue, 1 chunk ahead
            issue(cc + 1, n00, n01, n10, n11, v00, v01, v10, v11);

        const __bf16* a00 = (const __bf16*)&c00;
        const __bf16* a01 = (const __bf16*)&c01;
        const __bf16* a10 = (const __bf16*)&c10;
        const __bf16* a11 = (const __bf16*)&c11;
        bf16x8 bfrag;
#pragma unroll
        for (int ccc = 0; ccc < 8; ++ccc) {
            float v = w00 * (float)a00[ccc] + w01 * (float)a01[ccc]
                    + w10 * (float)a10[ccc] + w11 * (float)a11[ccc];
            bfrag[ccc] = (__bf16)v;     // compiler emits v_cvt_pk_bf16_f32 (RNE)
        }
#pragma unroll
        for (int mt = 0; mt < 4; ++mt) {
            bf16x8 afrag = __builtin_bit_cast(bf16x8, wq[((ch0 + cc) * 4 + mt) * 64 + lane]);
            acc[mt] = __builtin_amdgcn_mfma_f32_16x16x32_bf16(afrag, bfrag, acc[mt], 0, 0, 0);
        }
        if (cc + 1 < NCHALF) {
            c00 = n00; c01 = n01; c10 = n10; c11 = n11;
            w00 = v00; w01 = v01; w10 = v10; w11 = v11;
        }
    }

    // combine K-halves: half 1 publishes, half 0 reduces + stores
    if (half == 1) {
#pragma unroll
        for (int mt = 0; mt < 4; ++mt) lred[tile][mt][lane] = acc[mt];
    }
    __syncthreads();
    if (half == 1) return;

#pragma unroll
    for (int mt = 0; mt < 4; ++mt) {
        f32x4 pv = lred[tile][mt][lane];
        acc[mt][0] += pv[0]; acc[mt][1] += pv[1];
        acc[mt][2] += pv[2]; acc[mt][3] += pv[3];
    }

    // C/D layout: col = lane&15 (pixel), row = q*4 + r (out channel within 16-tile)
    const int rem_out = (pixbase & 16383) + n;
    float* outp = out + (size_t)b * COUTN * HOWO + rem_out;
#pragma unroll
    for (int mt = 0; mt < 4; ++mt) {
        f32x4 bv = *(const f32x4*)(bias + mt * 16 + q * 4);
#pragma unroll
        for (int r = 0; r < 4; ++r) {
            int o = mt * 16 + q * 4 + r;
            outp[(size_t)o * HOWO] = acc[mt][r] + bv[r];
        }
    }
}

extern "C" void kernel_launch(void* const* d_in, const int* in_sizes, int n_in,
                              void* d_out, int out_size, void* d_ws, size_t ws_size,
                              hipStream_t stream) {
    const float* x    = (const float*)d_in[0];
    const float* off  = (const float*)d_in[1];
    const float* wgt  = (const float*)d_in[2];
    const float* bias = (const float*)d_in[3];
    float* out = (float*)d_out;

    uint4* xh = (uint4*)d_ws;                                 // 8,921,088 B
    uint4* wq = (uint4*)((char*)d_ws + (size_t)NXG * 16);     // 73,728 B

    const int xblocks = (NXG + 255) / 256;                    // 2178
    prep<<<dim3(NWBLK + xblocks), dim3(256), 0, stream>>>(x, wgt, xh, wq);
    dcn_mfma<<<dim3(BB * HOWO / 32), dim3(256), 0, stream>>>(xh, off, wq, bias, out);
}

// Round 4
// 114.747 us; speedup vs baseline: 1.0893x; 1.0731x over previous
//
#include <hip/hip_runtime.h>

#define BB    4
#define CINT  64
#define HH    128
#define WW    128
#define COUTN 64
#define DGN   8
#define CGN   8
#define KKN   9
#define HOWO  16384
#define HWSZ  (HH * WW)
#define HP    132
#define WP    132
#define HWP   (HP * WP)          // 17424 granules per (b,g) plane, 2-wide zero border
#define NXG   (BB * DGN * HWP)   // 557568 granules = 8,921,088 B
#define NCHUNK 18                // K = 576 = 18 * 32
#define NSTAGE 12                // chunks whose A-fragments live in LDS (48 KB)
#define NWBLK  18                // weight-prep blocks (18*256 = 4608 entries)

typedef __bf16 bf16x8 __attribute__((ext_vector_type(8)));
typedef float  f32x4  __attribute__((ext_vector_type(4)));

static __device__ __forceinline__ ushort f2bf(float f) {
    unsigned u = __builtin_bit_cast(unsigned, f);
    u += 0x7fffu + ((u >> 16) & 1u);      // round-to-nearest-even
    return (ushort)(u >> 16);
}

// ---- fused prep: blocks [0,18) pack weights into MFMA A-fragment order;
// blocks [18,..) build zero-padded bf16 image xh [B][DG][132][132][CG].
__global__ __launch_bounds__(256) void prep(
    const float* __restrict__ x, const float* __restrict__ wgt,
    uint4* __restrict__ xh, uint4* __restrict__ wq)
{
    const int bid = blockIdx.x;
    const int tid = threadIdx.x;
    if (bid < NWBLK) {
        int i = bid * 256 + tid;            // 0..4607
        int lane = i & 63;
        int mt   = (i >> 6) & 3;
        int kt   = i >> 8;
        int m = lane & 15, quad = lane >> 4;
        int o = mt * 16 + m;
        union { ushort u[8]; uint4 v; } pk;
#pragma unroll
        for (int j = 0; j < 8; ++j) {
            int k   = kt * 32 + quad * 8 + j;
            int gkk = k >> 3, c = k & 7;
            int g   = gkk / 9, kk = gkk - 9 * g;
            pk.u[j] = f2bf(wgt[(o * CINT + g * CGN + c) * KKN + kk]);
        }
        wq[i] = pk.v;
        return;
    }
    int j = (bid - NWBLK) * 256 + tid;      // granule id
    if (j >= NXG) return;
    int bg = j / HWP;
    int r  = j - bg * HWP;
    int yp = r / WP;
    int xp = r - yp * WP;
    union { ushort u[8]; uint4 v; } pk;
    pk.v.x = pk.v.y = pk.v.z = pk.v.w = 0u;
    if (yp >= 2 && yp <= 129 && xp >= 2 && xp <= 129) {
        const float* src = x + (size_t)bg * CGN * HWSZ + (yp - 2) * WW + (xp - 2);
#pragma unroll
        for (int c = 0; c < CGN; ++c) pk.u[c] = f2bf(src[c * HWSZ]);
    }
    xh[j] = pk.v;
}

// ---- main: each wave owns 16 pixels; lane (q=lane>>4, n=lane&15) samples
// (pixel n, gkk = ch*4+q) -> its 8-channel B-fragment directly. A-fragments for
// chunks [0,12) staged in LDS (49,152 B, 3 blocks/CU); chunks [12,18) via L1.
__global__ __launch_bounds__(256, 3) void dcn_mfma(
    const uint4* __restrict__ xh, const float* __restrict__ off,
    const uint4* __restrict__ wq, const float* __restrict__ bias,
    float* __restrict__ out)
{
    __shared__ uint4 swq[NSTAGE * 4 * 64];   // 49,152 B, same linear layout as wq

    const int tid  = threadIdx.x;
    const int wave = tid >> 6;
    const int lane = tid & 63;
    const int q    = lane >> 4;         // k-quarter within 32-K chunk
    const int n    = lane & 15;         // pixel within wave tile

    const int wid     = blockIdx.x * 4 + wave;     // 0..4095
    const int pixbase = wid * 16;
    const int b       = pixbase >> 14;
    const int rem     = (pixbase & 16383) + n;
    const int ho = rem >> 7, wo = rem & 127;
    const float fy0 = (float)(ho - 1);
    const float fx0 = (float)(wo - 1);

    // stage A-fragments for chunks [0,12): coalesced, once per block
#pragma unroll
    for (int i = 0; i < NSTAGE; ++i) swq[tid + i * 256] = wq[tid + i * 256];

    // offset float index: (b*72 + gkk)*2*HOWO + rem (dy), +HOWO (dx); gkk = ch*4+q
    const float* offp = off + (size_t)(b * 72 + q) * 2 * HOWO + rem;

    float lofy[4], lofx[4];             // rotating 4-deep offset prefetch
#pragma unroll
    for (int c0 = 0; c0 < 4; ++c0) {
        lofy[c0] = offp[(size_t)c0 * 8 * HOWO];
        lofx[c0] = offp[(size_t)c0 * 8 * HOWO + HOWO];
    }

    f32x4 acc[4];
#pragma unroll
    for (int mt = 0; mt < 4; ++mt) acc[mt] = (f32x4){0.f, 0.f, 0.f, 0.f};

    const int xbase = b * DGN * HWP;    // granule base for batch b

    int g = 0, kk = q;                  // incremental gkk -> (g, kk)
    uint4 c00, c01, c10, c11, n00, n01, n10, n11;
    float w00, w01, w10, w11, v00, v01, v10, v11;

    auto issue = [&](int ch, uint4& r00, uint4& r01, uint4& r10, uint4& r11,
                     float& u00, float& u01, float& u10, float& u11) {
        int kh = (kk * 11) >> 5;        // kk/3 for kk in [0,9)
        int kw = kk - 3 * kh;
        float py  = fy0 + (float)kh + lofy[ch & 3];
        float pxx = fx0 + (float)kw + lofx[ch & 3];
        float y0f = floorf(py), x0f = floorf(pxx);
        float ly = py - y0f, lx = pxx - x0f;
        float hy = 1.f - ly, hx = 1.f - lx;
        u00 = hy * hx; u01 = hy * lx; u10 = ly * hx; u11 = ly * lx;
        int y0 = (int)y0f, x0 = (int)x0f;
        // clamp into [-2, 128]: with the 2-wide zero border every OOB corner reads 0
        y0 = min(max(y0, -2), HH);
        x0 = min(max(x0, -2), WW);
        const uint4* p = xh + (xbase + g * HWP + (y0 + 2) * WP + (x0 + 2));
        r00 = p[0]; r01 = p[1]; r10 = p[WP]; r11 = p[WP + 1];
        kk += 4; if (kk >= KKN) { kk -= KKN; ++g; }   // advance gkk by 4
    };

    issue(0, c00, c01, c10, c11, w00, w01, w10, w11);
    __syncthreads();                    // swq ready

#pragma unroll
    for (int ch = 0; ch < NCHUNK; ++ch) {
        if (ch + 4 < NCHUNK) {          // offset prefetch, 4 chunks ahead
            lofy[(ch + 4) & 3] = offp[(size_t)(ch + 4) * 8 * HOWO];
            lofx[(ch + 4) & 3] = offp[(size_t)(ch + 4) * 8 * HOWO + HOWO];
        }
        if (ch + 1 < NCHUNK)            // gather issue, 1 chunk ahead
            issue(ch + 1, n00, n01, n10, n11, v00, v01, v10, v11);

        const __bf16* a00 = (const __bf16*)&c00;
        const __bf16* a01 = (const __bf16*)&c01;
        const __bf16* a10 = (const __bf16*)&c10;
        const __bf16* a11 = (const __bf16*)&c11;
        bf16x8 bfrag;
#pragma unroll
        for (int cc = 0; cc < 8; ++cc) {
            float v = w00 * (float)a00[cc] + w01 * (float)a01[cc]
                    + w10 * (float)a10[cc] + w11 * (float)a11[cc];
            bfrag[cc] = (__bf16)v;      // compiler emits v_cvt_pk_bf16_f32 (RNE)
        }
#pragma unroll
        for (int mt = 0; mt < 4; ++mt) {
            const int idx = (ch * 4 + mt) * 64 + lane;
            uint4 av = (ch < NSTAGE) ? swq[idx] : wq[idx];   // folds at compile time
            bf16x8 afrag = __builtin_bit_cast(bf16x8, av);
            acc[mt] = __builtin_amdgcn_mfma_f32_16x16x32_bf16(afrag, bfrag, acc[mt], 0, 0, 0);
        }
        if (ch + 1 < NCHUNK) {
            c00 = n00; c01 = n01; c10 = n10; c11 = n11;
            w00 = v00; w01 = v01; w10 = v10; w11 = v11;
        }
    }

    // C/D layout: col = lane&15 (pixel), row = q*4 + r (out channel within 16-tile)
    const int rem_out = (pixbase & 16383) + n;
    float* outp = out + (size_t)b * COUTN * HOWO + rem_out;
#pragma unroll
    for (int mt = 0; mt < 4; ++mt) {
        f32x4 bv = *(const f32x4*)(bias + mt * 16 + q * 4);
#pragma unroll
        for (int r = 0; r < 4; ++r) {
            int o = mt * 16 + q * 4 + r;
            outp[(size_t)o * HOWO] = acc[mt][r] + bv[r];
        }
    }
}

extern "C" void kernel_launch(void* const* d_in, const int* in_sizes, int n_in,
                              void* d_out, int out_size, void* d_ws, size_t ws_size,
                              hipStream_t stream) {
    const float* x    = (const float*)d_in[0];
    const float* off  = (const float*)d_in[1];
    const float* wgt  = (const float*)d_in[2];
    const float* bias = (const float*)d_in[3];
    float* out = (float*)d_out;

    uint4* xh = (uint4*)d_ws;                                 // 8,921,088 B
    uint4* wq = (uint4*)((char*)d_ws + (size_t)NXG * 16);     // 73,728 B

    const int xblocks = (NXG + 255) / 256;                    // 2178
    prep<<<dim3(NWBLK + xblocks), dim3(256), 0, stream>>>(x, wgt, xh, wq);
    dcn_mfma<<<dim3(BB * HOWO / 64), dim3(256), 0, stream>>>(xh, off, wq, bias, out);
}

// Round 5
// 113.868 us; speedup vs baseline: 1.0977x; 1.0077x over previous
//
#include <hip/hip_runtime.h>

#define BB    4
#define CINT  64
#define HH    128
#define WW    128
#define COUTN 64
#define DGN   8
#define CGN   8
#define KKN   9
#define HOWO  16384
#define HWSZ  (HH * WW)
#define HP    132
#define WP    132
#define HWP   (HP * WP)          // 17424 granules per (b,g) plane, 2-wide zero border
#define NXG   (BB * DGN * HWP)   // 557568 granules = 8,921,088 B
#define NCHUNK 18                // K = 576 = 18 * 32
#define NSTAGE 12                // chunks whose A-fragments live in LDS (48 KB < 64 KB limit)
#define NWBLK  18                // weight-prep blocks (18*256 = 4608 entries)

typedef _Float16 f16x8 __attribute__((ext_vector_type(8)));
typedef _Float16 h2    __attribute__((ext_vector_type(2)));
typedef float    f32x4 __attribute__((ext_vector_type(4)));

static __device__ __forceinline__ ushort f2h(float f) {
    _Float16 h = (_Float16)f;
    return __builtin_bit_cast(ushort, h);
}

// ---- fused prep: blocks [0,18) pack weights into MFMA A-fragment order (f16);
// blocks [18,..) build zero-padded f16 image xh [B][DG][132][132][CG].
__global__ __launch_bounds__(256) void prep(
    const float* __restrict__ x, const float* __restrict__ wgt,
    uint4* __restrict__ xh, uint4* __restrict__ wq)
{
    const int bid = blockIdx.x;
    const int tid = threadIdx.x;
    if (bid < NWBLK) {
        int i = bid * 256 + tid;            // 0..4607
        int lane = i & 63;
        int mt   = (i >> 6) & 3;
        int kt   = i >> 8;
        int m = lane & 15, quad = lane >> 4;
        int o = mt * 16 + m;
        union { ushort u[8]; uint4 v; } pk;
#pragma unroll
        for (int j = 0; j < 8; ++j) {
            int k   = kt * 32 + quad * 8 + j;
            int gkk = k >> 3, c = k & 7;
            int g   = gkk / 9, kk = gkk - 9 * g;
            pk.u[j] = f2h(wgt[(o * CINT + g * CGN + c) * KKN + kk]);
        }
        wq[i] = pk.v;
        return;
    }
    int j = (bid - NWBLK) * 256 + tid;      // granule id
    if (j >= NXG) return;
    int bg = j / HWP;
    int r  = j - bg * HWP;
    int yp = r / WP;
    int xp = r - yp * WP;
    union { ushort u[8]; uint4 v; } pk;
    pk.v.x = pk.v.y = pk.v.z = pk.v.w = 0u;
    if (yp >= 2 && yp <= 129 && xp >= 2 && xp <= 129) {
        const float* src = x + (size_t)bg * CGN * HWSZ + (yp - 2) * WW + (xp - 2);
#pragma unroll
        for (int c = 0; c < CGN; ++c) pk.u[c] = f2h(src[c * HWSZ]);
    }
    xh[j] = pk.v;
}

// ---- main: each wave owns 16 pixels; lane (q=lane>>4, n=lane&15) samples
// (pixel n, gkk = ch*4+q) -> its 8-channel B-fragment in-register. Bilinear in
// packed f16 (v_pk_fma_f16); A-fragments chunks [0,12) in LDS, [12,18) via L1.
__global__ __launch_bounds__(256, 3) void dcn_mfma(
    const uint4* __restrict__ xh, const float* __restrict__ off,
    const uint4* __restrict__ wq, const float* __restrict__ bias,
    float* __restrict__ out)
{
    __shared__ uint4 swq[NSTAGE * 4 * 64];   // 49,152 B, same linear layout as wq

    const int tid  = threadIdx.x;
    const int wave = tid >> 6;
    const int lane = tid & 63;
    const int q    = lane >> 4;         // k-quarter within 32-K chunk
    const int n    = lane & 15;         // pixel within wave tile

    const int wid     = blockIdx.x * 4 + wave;     // 0..4095
    const int pixbase = wid * 16;
    const int b       = pixbase >> 14;
    const int rem     = (pixbase & 16383) + n;
    const int ho = rem >> 7, wo = rem & 127;
    const float fy0 = (float)(ho - 1);
    const float fx0 = (float)(wo - 1);

    // stage A-fragments for chunks [0,12): coalesced, once per block
#pragma unroll
    for (int i = 0; i < NSTAGE; ++i) swq[tid + i * 256] = wq[tid + i * 256];

    // offset float index: (b*72 + gkk)*2*HOWO + rem (dy), +HOWO (dx); gkk = ch*4+q
    const float* offp = off + (size_t)(b * 72 + q) * 2 * HOWO + rem;

    float lofy[4], lofx[4];             // rotating 4-deep offset prefetch
#pragma unroll
    for (int c0 = 0; c0 < 4; ++c0) {
        lofy[c0] = offp[(size_t)c0 * 8 * HOWO];
        lofx[c0] = offp[(size_t)c0 * 8 * HOWO + HOWO];
    }

    f32x4 acc[4];
#pragma unroll
    for (int mt = 0; mt < 4; ++mt) acc[mt] = (f32x4){0.f, 0.f, 0.f, 0.f};

    const int xbase = b * DGN * HWP;    // granule base for batch b

    int g = 0, kk = q;                  // incremental gkk -> (g, kk)
    uint4 c00, c01, c10, c11, n00, n01, n10, n11;
    h2 cw00, cw01, cw10, cw11, nw00, nw01, nw10, nw11;

    auto issue = [&](int ch, uint4& r00, uint4& r01, uint4& r10, uint4& r11,
                     h2& u00, h2& u01, h2& u10, h2& u11) {
        int kh = (kk * 11) >> 5;        // kk/3 for kk in [0,9)
        int kw = kk - 3 * kh;
        float py  = fy0 + (float)kh + lofy[ch & 3];
        float pxx = fx0 + (float)kw + lofx[ch & 3];
        float y0f = floorf(py), x0f = floorf(pxx);
        float ly = py - y0f, lx = pxx - x0f;
        float hy = 1.f - ly, hx = 1.f - lx;
        _Float16 w00 = (_Float16)(hy * hx), w01 = (_Float16)(hy * lx);
        _Float16 w10 = (_Float16)(ly * hx), w11 = (_Float16)(ly * lx);
        u00 = (h2){w00, w00}; u01 = (h2){w01, w01};
        u10 = (h2){w10, w10}; u11 = (h2){w11, w11};
        int y0 = (int)y0f, x0 = (int)x0f;
        // clamp into [-2, 128]: with the 2-wide zero border every OOB corner reads 0
        y0 = min(max(y0, -2), HH);
        x0 = min(max(x0, -2), WW);
        const uint4* p = xh + (xbase + g * HWP + (y0 + 2) * WP + (x0 + 2));
        r00 = p[0]; r01 = p[1]; r10 = p[WP]; r11 = p[WP + 1];
        kk += 4; if (kk >= KKN) { kk -= KKN; ++g; }   // advance gkk by 4
    };

    issue(0, c00, c01, c10, c11, cw00, cw01, cw10, cw11);
    __syncthreads();                    // swq ready

#pragma unroll
    for (int ch = 0; ch < NCHUNK; ++ch) {
        if (ch + 4 < NCHUNK) {          // offset prefetch, 4 chunks ahead
            lofy[(ch + 4) & 3] = offp[(size_t)(ch + 4) * 8 * HOWO];
            lofx[(ch + 4) & 3] = offp[(size_t)(ch + 4) * 8 * HOWO + HOWO];
        }
        if (ch + 1 < NCHUNK)            // gather issue, 1 chunk ahead
            issue(ch + 1, n00, n01, n10, n11, nw00, nw01, nw10, nw11);

        const h2* p00 = (const h2*)&c00;
        const h2* p01 = (const h2*)&c01;
        const h2* p10 = (const h2*)&c10;
        const h2* p11 = (const h2*)&c11;
        f16x8 bfrag;
        h2* bp = (h2*)&bfrag;
#pragma unroll
        for (int j = 0; j < 4; ++j)
            bp[j] = cw00 * p00[j] + cw01 * p01[j]
                  + cw10 * p10[j] + cw11 * p11[j];   // v_pk_mul/fma_f16

#pragma unroll
        for (int mt = 0; mt < 4; ++mt) {
            const int idx = (ch * 4 + mt) * 64 + lane;
            uint4 av = (ch < NSTAGE) ? swq[idx] : wq[idx];   // folds at compile time
            f16x8 afrag = __builtin_bit_cast(f16x8, av);
            acc[mt] = __builtin_amdgcn_mfma_f32_16x16x32_f16(afrag, bfrag, acc[mt], 0, 0, 0);
        }
        if (ch + 1 < NCHUNK) {
            c00 = n00; c01 = n01; c10 = n10; c11 = n11;
            cw00 = nw00; cw01 = nw01; cw10 = nw10; cw11 = nw11;
        }
    }

    // C/D layout: col = lane&15 (pixel), row = q*4 + r (out channel within 16-tile)
    const int rem_out = (pixbase & 16383) + n;
    float* outp = out + (size_t)b * COUTN * HOWO + rem_out;
#pragma unroll
    for (int mt = 0; mt < 4; ++mt) {
        f32x4 bv = *(const f32x4*)(bias + mt * 16 + q * 4);
#pragma unroll
        for (int r = 0; r < 4; ++r) {
            int o = mt * 16 + q * 4 + r;
            outp[(size_t)o * HOWO] = acc[mt][r] + bv[r];
        }
    }
}

extern "C" void kernel_launch(void* const* d_in, const int* in_sizes, int n_in,
                              void* d_out, int out_size, void* d_ws, size_t ws_size,
                              hipStream_t stream) {
    const float* x    = (const float*)d_in[0];
    const float* off  = (const float*)d_in[1];
    const float* wgt  = (const float*)d_in[2];
    const float* bias = (const float*)d_in[3];
    float* out = (float*)d_out;

    uint4* xh = (uint4*)d_ws;                                 // 8,921,088 B
    uint4* wq = (uint4*)((char*)d_ws + (size_t)NXG * 16);     // 73,728 B

    const int xblocks = (NXG + 255) / 256;                    // 2178
    prep<<<dim3(NWBLK + xblocks), dim3(256), 0, stream>>>(x, wgt, xh, wq);
    dcn_mfma<<<dim3(BB * HOWO / 64), dim3(256), 0, stream>>>(xh, off, wq, bias, out);
}

// Round 6
// 112.131 us; speedup vs baseline: 1.1147x; 1.0155x over previous
//
#include <hip/hip_runtime.h>

#define BB    4
#define CINT  64
#define HH    128
#define WW    128
#define COUTN 64
#define DGN   8
#define CGN   8
#define KKN   9
#define HOWO  16384
#define HWSZ  (HH * WW)
#define HP    132
#define WP    132
#define HWP   (HP * WP)          // 17424 granules per (b,g) plane, 2-wide zero border
#define NXG   (BB * DGN * HWP)   // 557568 granules = 8,921,088 B
#define NCHUNK 18                // K = 576 = 18 * 32
#define NSTAGE 12                // chunks whose A-fragments live in LDS (48 KB < 64 KB limit)
#define NWBLK  18                // weight-prep blocks (18*256 = 4608 entries)

typedef _Float16 f16x8 __attribute__((ext_vector_type(8)));
typedef _Float16 h2    __attribute__((ext_vector_type(2)));
typedef float    f32x4 __attribute__((ext_vector_type(4)));

static __device__ __forceinline__ ushort f2h(float f) {
    _Float16 h = (_Float16)f;
    return __builtin_bit_cast(ushort, h);
}

// ---- fused prep: blocks [0,18) pack weights into MFMA A-fragment order (f16);
// blocks [18,..) build zero-padded f16 image xh [B][DG][132][132][CG].
__global__ __launch_bounds__(256) void prep(
    const float* __restrict__ x, const float* __restrict__ wgt,
    uint4* __restrict__ xh, uint4* __restrict__ wq)
{
    const int bid = blockIdx.x;
    const int tid = threadIdx.x;
    if (bid < NWBLK) {
        int i = bid * 256 + tid;            // 0..4607
        int lane = i & 63;
        int mt   = (i >> 6) & 3;
        int kt   = i >> 8;
        int m = lane & 15, quad = lane >> 4;
        int o = mt * 16 + m;
        union { ushort u[8]; uint4 v; } pk;
#pragma unroll
        for (int j = 0; j < 8; ++j) {
            int k   = kt * 32 + quad * 8 + j;
            int gkk = k >> 3, c = k & 7;
            int g   = gkk / 9, kk = gkk - 9 * g;
            pk.u[j] = f2h(wgt[(o * CINT + g * CGN + c) * KKN + kk]);
        }
        wq[i] = pk.v;
        return;
    }
    int j = (bid - NWBLK) * 256 + tid;      // granule id
    if (j >= NXG) return;
    int bg = j / HWP;
    int r  = j - bg * HWP;
    int yp = r / WP;
    int xp = r - yp * WP;
    union { ushort u[8]; uint4 v; } pk;
    pk.v.x = pk.v.y = pk.v.z = pk.v.w = 0u;
    if (yp >= 2 && yp <= 129 && xp >= 2 && xp <= 129) {
        const float* src = x + (size_t)bg * CGN * HWSZ + (yp - 2) * WW + (xp - 2);
#pragma unroll
        for (int c = 0; c < CGN; ++c) pk.u[c] = f2h(src[c * HWSZ]);
    }
    xh[j] = pk.v;
}

// ---- main: each wave owns 16 pixels; lane (q=lane>>4, n=lane&15) samples
// (pixel n, gkk = ch*4+q) -> its 8-channel B-fragment in-register. Bilinear in
// packed f16; A-fragments chunks [0,12) in LDS, [12,18) via L1.
// 2-deep gather pipeline: consume slot, then reissue it for ch+2.
__global__ __launch_bounds__(256, 3) void dcn_mfma(
    const uint4* __restrict__ xh, const float* __restrict__ off,
    const uint4* __restrict__ wq, const float* __restrict__ bias,
    float* __restrict__ out)
{
    __shared__ uint4 swq[NSTAGE * 4 * 64];   // 49,152 B, same linear layout as wq

    const int tid  = threadIdx.x;
    const int wave = tid >> 6;
    const int lane = tid & 63;
    const int q    = lane >> 4;         // k-quarter within 32-K chunk
    const int n    = lane & 15;         // pixel within wave tile

    const int wid     = blockIdx.x * 4 + wave;     // 0..4095
    const int pixbase = wid * 16;
    const int b       = pixbase >> 14;
    const int rem     = (pixbase & 16383) + n;
    const int ho = rem >> 7, wo = rem & 127;
    const float fy0 = (float)(ho - 1);
    const float fx0 = (float)(wo - 1);

    // stage A-fragments for chunks [0,12): coalesced, once per block
#pragma unroll
    for (int i = 0; i < NSTAGE; ++i) swq[tid + i * 256] = wq[tid + i * 256];

    // offset float index: (b*72 + gkk)*2*HOWO + rem (dy), +HOWO (dx); gkk = ch*4+q
    const float* offp = off + (size_t)(b * 72 + q) * 2 * HOWO + rem;

    float lofy[8], lofx[8];             // rotating 6-ahead offset prefetch
#pragma unroll
    for (int c0 = 0; c0 < 6; ++c0) {
        lofy[c0] = offp[(size_t)c0 * 8 * HOWO];
        lofx[c0] = offp[(size_t)c0 * 8 * HOWO + HOWO];
    }
    lofy[6] = 0.f; lofx[6] = 0.f; lofy[7] = 0.f; lofx[7] = 0.f;

    f32x4 acc[4];
#pragma unroll
    for (int mt = 0; mt < 4; ++mt) acc[mt] = (f32x4){0.f, 0.f, 0.f, 0.f};

    const int xbase = b * DGN * HWP;    // granule base for batch b

    int g = 0, kk = q;                  // incremental gkk -> (g, kk)
    uint4 sb00[2], sb01[2], sb10[2], sb11[2];   // 2 gather slots (static idx under unroll)
    h2   sw[2][4];

    auto issue = [&](int ch, int s) {
        int kh = (kk * 11) >> 5;        // kk/3 for kk in [0,9)
        int kw = kk - 3 * kh;
        float py  = fy0 + (float)kh + lofy[ch & 7];
        float pxx = fx0 + (float)kw + lofx[ch & 7];
        float y0f = floorf(py), x0f = floorf(pxx);
        float ly = py - y0f, lx = pxx - x0f;
        float hy = 1.f - ly, hx = 1.f - lx;
        _Float16 w00 = (_Float16)(hy * hx), w01 = (_Float16)(hy * lx);
        _Float16 w10 = (_Float16)(ly * hx), w11 = (_Float16)(ly * lx);
        sw[s][0] = (h2){w00, w00}; sw[s][1] = (h2){w01, w01};
        sw[s][2] = (h2){w10, w10}; sw[s][3] = (h2){w11, w11};
        int y0 = (int)y0f, x0 = (int)x0f;
        // clamp into [-2, 128]: with the 2-wide zero border every OOB corner reads 0
        y0 = min(max(y0, -2), HH);
        x0 = min(max(x0, -2), WW);
        const uint4* p = xh + (xbase + g * HWP + (y0 + 2) * WP + (x0 + 2));
        sb00[s] = p[0]; sb01[s] = p[1]; sb10[s] = p[WP]; sb11[s] = p[WP + 1];
        kk += 4; if (kk >= KKN) { kk -= KKN; ++g; }   // advance gkk by 4
    };

    issue(0, 0);                        // slot0 <- chunk 0
    issue(1, 1);                        // slot1 <- chunk 1
    __syncthreads();                    // swq ready

#pragma unroll
    for (int ch = 0; ch < NCHUNK; ++ch) {
        const int s = ch & 1;

        // 1. consume slot s (chunk ch) into bfrag
        const h2* p00 = (const h2*)&sb00[s];
        const h2* p01 = (const h2*)&sb01[s];
        const h2* p10 = (const h2*)&sb10[s];
        const h2* p11 = (const h2*)&sb11[s];
        h2 u00 = sw[s][0], u01 = sw[s][1], u10 = sw[s][2], u11 = sw[s][3];
        f16x8 bfrag;
        h2* bp = (h2*)&bfrag;
#pragma unroll
        for (int j = 0; j < 4; ++j)
            bp[j] = u00 * p00[j] + u01 * p01[j]
                  + u10 * p10[j] + u11 * p11[j];   // v_pk_mul/fma_f16

        // 2. reissue slot s for chunk ch+2 (2 chunks now in flight)
        if (ch + 2 < NCHUNK) issue(ch + 2, s);

        // 3. offset prefetch, 6 chunks ahead
        if (ch + 6 < NCHUNK) {
            lofy[(ch + 6) & 7] = offp[(size_t)(ch + 6) * 8 * HOWO];
            lofx[(ch + 6) & 7] = offp[(size_t)(ch + 6) * 8 * HOWO + HOWO];
        }

        // 4. MFMA cluster
#pragma unroll
        for (int mt = 0; mt < 4; ++mt) {
            const int idx = (ch * 4 + mt) * 64 + lane;
            uint4 av = (ch < NSTAGE) ? swq[idx] : wq[idx];   // folds at compile time
            f16x8 afrag = __builtin_bit_cast(f16x8, av);
            acc[mt] = __builtin_amdgcn_mfma_f32_16x16x32_f16(afrag, bfrag, acc[mt], 0, 0, 0);
        }
    }

    // C/D layout: col = lane&15 (pixel), row = q*4 + r (out channel within 16-tile)
    const int rem_out = (pixbase & 16383) + n;
    float* outp = out + (size_t)b * COUTN * HOWO + rem_out;
#pragma unroll
    for (int mt = 0; mt < 4; ++mt) {
        f32x4 bv = *(const f32x4*)(bias + mt * 16 + q * 4);
#pragma unroll
        for (int r = 0; r < 4; ++r) {
            int o = mt * 16 + q * 4 + r;
            outp[(size_t)o * HOWO] = acc[mt][r] + bv[r];
        }
    }
}

extern "C" void kernel_launch(void* const* d_in, const int* in_sizes, int n_in,
                              void* d_out, int out_size, void* d_ws, size_t ws_size,
                              hipStream_t stream) {
    const float* x    = (const float*)d_in[0];
    const float* off  = (const float*)d_in[1];
    const float* wgt  = (const float*)d_in[2];
    const float* bias = (const float*)d_in[3];
    float* out = (float*)d_out;

    uint4* xh = (uint4*)d_ws;                                 // 8,921,088 B
    uint4* wq = (uint4*)((char*)d_ws + (size_t)NXG * 16);     // 73,728 B

    const int xblocks = (NXG + 255) / 256;                    // 2178
    prep<<<dim3(NWBLK + xblocks), dim3(256), 0, stream>>>(x, wgt, xh, wq);
    dcn_mfma<<<dim3(BB * HOWO / 64), dim3(256), 0, stream>>>(xh, off, wq, bias, out);
}